// Round 1
// 5839.551 us; speedup vs baseline: 1.0669x; 1.0669x over previous
//
#include <hip/hip_runtime.h>

#define BT 2
#define LSEQ 1024
#define TT 2048      // total tokens
#define DM 768
#define DI 1536
#define DI2 3072
#define DS 16
#define DR 48
#define NL 4
#define VOC 32000
#define EPSV 1e-5f

typedef __attribute__((ext_vector_type(8))) short short8;
typedef __attribute__((ext_vector_type(4))) float f32x4;

__device__ __forceinline__ short f2b(float f) {
  unsigned u = __float_as_uint(f);
  unsigned r = (u + 0x7FFFu + ((u >> 16) & 1u)) >> 16;   // round-to-nearest-even
  return (short)r;
}
__device__ __forceinline__ float b2f(short s) {
  return __uint_as_float(((unsigned)(unsigned short)s) << 16);
}

// split 8 consecutive fp32 into hi/lo bf16 fragments (x ~= hi + lo, err ~2^-17)
__device__ __forceinline__ void split8(const float* __restrict__ p, short8& hi, short8& lo) {
  f32x4 v0 = *(const f32x4*)p;
  f32x4 v1 = *(const f32x4*)(p + 4);
  float f[8] = {v0[0], v0[1], v0[2], v0[3], v1[0], v1[1], v1[2], v1[3]};
#pragma unroll
  for (int j = 0; j < 8; j++) {
    short h = f2b(f[j]);
    hi[j] = h;
    lo[j] = f2b(f[j] - b2f(h));
  }
}

// ---------------- one-time weight split: fp32 -> bf16 hi/lo ----------------
__global__ void k_split(const float* __restrict__ in, short* __restrict__ hi,
                        short* __restrict__ lo) {
  size_t i = ((size_t)blockIdx.x * 256 + threadIdx.x) * 8;
  short8 h, l;
  split8(in + i, h, l);
  *(short8*)(hi + i) = h;
  *(short8*)(lo + i) = l;
}

// ---------------- embedding gather -> fp32 residual stream ----------------
__global__ void k_embed(const int* __restrict__ ids, const float* __restrict__ emb,
                        float* __restrict__ x) {
  int idx = blockIdx.x * 256 + threadIdx.x;
  int t = idx / DM, c = idx % DM;
  x[idx] = emb[(size_t)ids[t] * DM + c];
}

// ---------------- rmsnorm (fp32 -> bf16 hi/lo) ----------------
__global__ void k_rmsnorm(const float* __restrict__ x, const float* __restrict__ w,
                          short* __restrict__ oh, short* __restrict__ ol) {
  int t = blockIdx.x;
  const float* xrow = x + (size_t)t * DM;
  float v[3];
  float p = 0.f;
#pragma unroll
  for (int k = 0; k < 3; k++) {
    v[k] = xrow[threadIdx.x + k * 256];
    p += v[k] * v[k];
  }
  for (int o = 32; o; o >>= 1) p += __shfl_down(p, o, 64);
  __shared__ float sred[4];
  int wave = threadIdx.x >> 6, lane = threadIdx.x & 63;
  if (lane == 0) sred[wave] = p;
  __syncthreads();
  float ss = sred[0] + sred[1] + sred[2] + sred[3];
  float sc = rsqrtf(ss / (float)DM + EPSV);
#pragma unroll
  for (int k = 0; k < 3; k++) {
    int c = threadIdx.x + k * 256;
    float f = v[k] * sc * w[c];
    short h = f2b(f);
    oh[(size_t)t * DM + c] = h;
    ol[(size_t)t * DM + c] = f2b(f - b2f(h));
  }
}

// ------- GEMM: C[M,N] = A[M,K] * W[N,K]^T, pre-split bf16 hi/lo operands -------
// 3 MFMAs per fragment pair: ah*bh + ah*bl + al*bh  (drops lo*lo ~ 2^-32)
// wave tile 32x64 (2x4 frags), block 64x128.
// MODE 0: store    MODE 1: += (residual)
template <int MODE>
__global__ void __launch_bounds__(256)
k_gemm(const short* __restrict__ Ahi, const short* __restrict__ Alo,
       const short* __restrict__ Bhi, const short* __restrict__ Blo,
       float* __restrict__ C, int N, int K) {
  int lane = threadIdx.x & 63;
  int wave = threadIdx.x >> 6;
  int quad = lane >> 4;
  int l16 = lane & 15;
  int bm = blockIdx.x * 64 + (wave >> 1) * 32;
  int bn = blockIdx.y * 128 + (wave & 1) * 64;
  f32x4 acc[2][4] = {};
  const short* aph[2];
  const short* apl[2];
  const short* bph[4];
  const short* bpl[4];
#pragma unroll
  for (int i = 0; i < 2; i++) {
    size_t r = (size_t)(bm + i * 16 + l16) * K + quad * 8;
    aph[i] = Ahi + r;
    apl[i] = Alo + r;
  }
#pragma unroll
  for (int j = 0; j < 4; j++) {
    size_t r = (size_t)(bn + j * 16 + l16) * K + quad * 8;
    bph[j] = Bhi + r;
    bpl[j] = Blo + r;
  }
  for (int k0 = 0; k0 < K; k0 += 32) {
    short8 ah[2], al[2], bh[4], bl[4];
#pragma unroll
    for (int i = 0; i < 2; i++) {
      ah[i] = *(const short8*)(aph[i] + k0);
      al[i] = *(const short8*)(apl[i] + k0);
    }
#pragma unroll
    for (int j = 0; j < 4; j++) {
      bh[j] = *(const short8*)(bph[j] + k0);
      bl[j] = *(const short8*)(bpl[j] + k0);
    }
#pragma unroll
    for (int i = 0; i < 2; i++)
#pragma unroll
      for (int j = 0; j < 4; j++) {
        acc[i][j] = __builtin_amdgcn_mfma_f32_16x16x32_bf16(ah[i], bh[j], acc[i][j], 0, 0, 0);
        acc[i][j] = __builtin_amdgcn_mfma_f32_16x16x32_bf16(ah[i], bl[j], acc[i][j], 0, 0, 0);
        acc[i][j] = __builtin_amdgcn_mfma_f32_16x16x32_bf16(al[i], bh[j], acc[i][j], 0, 0, 0);
      }
  }
#pragma unroll
  for (int i = 0; i < 2; i++)
#pragma unroll
    for (int j = 0; j < 4; j++) {
      int m0 = bm + i * 16 + quad * 4;
      int n = bn + j * 16 + l16;
#pragma unroll
      for (int r = 0; r < 4; r++) {
        size_t off = (size_t)(m0 + r) * N + n;
        float v = acc[i][j][r];
        if (MODE == 0) C[off] = v;
        else C[off] += v;
      }
    }
}

// ---------------- causal depthwise conv1d + bias + silu ----------------
__global__ void k_conv_silu(const float* __restrict__ xr, const float* __restrict__ cw,
                            const float* __restrict__ cb, float* __restrict__ u) {
  int idx = blockIdx.x * 256 + threadIdx.x;
  int t = idx / DI, d = idx % DI;
  int l = t & (LSEQ - 1);
  float acc = cb[d];
#pragma unroll
  for (int j = 0; j < 4; j++) {
    int ll = l - 3 + j;
    if (ll >= 0) acc += xr[(size_t)(t - 3 + j) * DI2 + d] * cw[d * 4 + j];
  }
  u[idx] = acc / (1.f + __expf(-acc));
}

// ---------------- x_proj: (1536) -> (80) per token ----------------
__global__ void __launch_bounds__(128)
k_xproj(const float* __restrict__ u, const float* __restrict__ w, float* __restrict__ xdbl) {
  __shared__ float su[DI];
  int t = blockIdx.x;
  for (int k = threadIdx.x; k < DI; k += 128) su[k] = u[(size_t)t * DI + k];
  __syncthreads();
  int o = threadIdx.x;
  if (o < 80) {
    const float* wr = w + (size_t)o * DI;
    float acc = 0.f;
    for (int k = 0; k < DI; k += 4) {
      f32x4 wv = *(const f32x4*)(wr + k);
      acc += su[k] * wv[0] + su[k + 1] * wv[1] + su[k + 2] * wv[2] + su[k + 3] * wv[3];
    }
    xdbl[(size_t)t * 80 + o] = acc;
  }
}

// ---------------- dt_proj (48 -> 1536) + softplus ----------------
__global__ void __launch_bounds__(256)
k_dtproj(const float* __restrict__ xdbl, const float* __restrict__ w,
         const float* __restrict__ bias, float* __restrict__ delta) {
  __shared__ float sd[DR];
  int t = blockIdx.y;
  int d = blockIdx.x * 256 + threadIdx.x;
  if (threadIdx.x < DR) sd[threadIdx.x] = xdbl[(size_t)t * 80 + threadIdx.x];
  __syncthreads();
  const float* wr = w + (size_t)d * DR;
  float acc = bias[d];
#pragma unroll
  for (int k = 0; k < DR; k += 4) {
    f32x4 wv = *(const f32x4*)(wr + k);
    acc += sd[k] * wv[0] + sd[k + 1] * wv[1] + sd[k + 2] * wv[2] + sd[k + 3] * wv[3];
  }
  float sp = (acc > 20.f) ? acc : log1pf(__expf(acc));
  delta[(size_t)t * DI + d] = sp;
}

// ---------------- selective scan: 16 lanes per channel (one per state) ----
// fused epilogue: y = (scan + D*u) * silu(res), bf16 hi/lo out for out_proj
__global__ void __launch_bounds__(256)
k_scan(const float* __restrict__ delta, const float* __restrict__ u,
       const float* __restrict__ xdbl, const float* __restrict__ xr,
       const float* __restrict__ A_log, const float* __restrict__ Dp,
       short* __restrict__ yh, short* __restrict__ yl) {
  int tid = threadIdx.x;
  int n = tid & 15;
  int ch = blockIdx.x * 16 + (tid >> 4);
  int b = ch / DI, d = ch % DI;
  float An = -__expf(A_log[d * DS + n]);
  float Dd = Dp[d];
  const float* dp = delta + (size_t)b * LSEQ * DI + d;
  const float* up = u + (size_t)b * LSEQ * DI + d;
  const float* xd = xdbl + (size_t)b * LSEQ * 80;
  const float* rp = xr + (size_t)b * LSEQ * DI2 + DI + d;
  short* yph = yh + (size_t)b * LSEQ * DI + d;
  short* ypl = yl + (size_t)b * LSEQ * DI + d;
  float h = 0.f;
  for (int l = 0; l < LSEQ; l++) {
    float dt = dp[(size_t)l * DI];
    float uu = up[(size_t)l * DI];
    float Bn = xd[l * 80 + DR + n];
    float Cn = xd[l * 80 + DR + DS + n];
    float dA = __expf(dt * An);
    h = fmaf(dA, h, dt * Bn * uu);
    float p = h * Cn;
    p += __shfl_xor(p, 1, 16);
    p += __shfl_xor(p, 2, 16);
    p += __shfl_xor(p, 4, 16);
    p += __shfl_xor(p, 8, 16);
    if (n == 0) {
      float res = rp[(size_t)l * DI2];
      float yv = fmaf(Dd, uu, p) * (res / (1.f + __expf(-res)));
      short hh = f2b(yv);
      yph[(size_t)l * DI] = hh;
      ypl[(size_t)l * DI] = f2b(yv - b2f(hh));
    }
  }
}

extern "C" void kernel_launch(void* const* d_in, const int* in_sizes, int n_in,
                              void* d_out, int out_size, void* d_ws, size_t ws_size,
                              hipStream_t stream) {
  const int* ids = (const int*)d_in[0];
  const float* emb = (const float*)d_in[4];
  const float* norm_w = (const float*)d_in[5];
  const float* in_proj_w = (const float*)d_in[6];
  const float* conv_w = (const float*)d_in[7];
  const float* conv_b = (const float*)d_in[8];
  const float* x_proj_w = (const float*)d_in[9];
  const float* dt_proj_w = (const float*)d_in[10];
  const float* dt_proj_b = (const float*)d_in[11];
  const float* A_log = (const float*)d_in[12];
  const float* D_param = (const float*)d_in[13];
  const float* out_proj_w = (const float*)d_in[14];
  const float* norm_f_w = (const float*)d_in[15];

  char* wp = (char*)d_ws;
  float* x = (float*)wp;    wp += (size_t)TT * DM * 4;
  float* xr = (float*)wp;   wp += (size_t)TT * DI2 * 4;
  float* u = (float*)wp;    wp += (size_t)TT * DI * 4;
  float* dl = (float*)wp;   wp += (size_t)TT * DI * 4;
  float* xdbl = (float*)wp; wp += (size_t)TT * 80 * 4;
  short* xnh = (short*)wp;  wp += (size_t)TT * DM * 2;
  short* xnl = (short*)wp;  wp += (size_t)TT * DM * 2;
  short* yh = (short*)wp;   wp += (size_t)TT * DI * 2;
  short* yl = (short*)wp;   wp += (size_t)TT * DI * 2;
  short* embh = (short*)wp; wp += (size_t)VOC * DM * 2;
  short* embl = (short*)wp; wp += (size_t)VOC * DM * 2;
  short* iph = (short*)wp;  wp += (size_t)NL * DI2 * DM * 2;
  short* ipl = (short*)wp;  wp += (size_t)NL * DI2 * DM * 2;
  short* oph = (short*)wp;  wp += (size_t)NL * DM * DI * 2;
  short* opl = (short*)wp;  wp += (size_t)NL * DM * DI * 2;

  // one-time (per launch) weight splits: fp32 -> bf16 hi/lo
  k_split<<<(VOC * DM) / 2048, 256, 0, stream>>>(emb, embh, embl);
  k_split<<<(NL * DI2 * DM) / 2048, 256, 0, stream>>>(in_proj_w, iph, ipl);
  k_split<<<(NL * DM * DI) / 2048, 256, 0, stream>>>(out_proj_w, oph, opl);

  k_embed<<<TT * DM / 256, 256, 0, stream>>>(ids, emb, x);
  for (int i = 0; i < NL; i++) {
    k_rmsnorm<<<TT, 256, 0, stream>>>(x, norm_w + (size_t)i * DM, xnh, xnl);
    k_gemm<0><<<dim3(TT / 64, DI2 / 128), 256, 0, stream>>>(
        xnh, xnl, iph + (size_t)i * DI2 * DM, ipl + (size_t)i * DI2 * DM, xr, DI2, DM);
    k_conv_silu<<<TT * DI / 256, 256, 0, stream>>>(
        xr, conv_w + (size_t)i * DI * 4, conv_b + (size_t)i * DI, u);
    k_xproj<<<TT, 128, 0, stream>>>(u, x_proj_w + (size_t)i * 80 * DI, xdbl);
    k_dtproj<<<dim3(DI / 256, TT), 256, 0, stream>>>(
        xdbl, dt_proj_w + (size_t)i * DI * DR, dt_proj_b + (size_t)i * DI, dl);
    k_scan<<<BT * DI / 16, 256, 0, stream>>>(
        dl, u, xdbl, xr, A_log + (size_t)i * DI * DS, D_param + (size_t)i * DI, yh, yl);
    k_gemm<1><<<dim3(TT / 64, DM / 128), 256, 0, stream>>>(
        yh, yl, oph + (size_t)i * DM * DI, opl + (size_t)i * DM * DI, x, DM, DI);
  }
  k_rmsnorm<<<TT, 256, 0, stream>>>(x, norm_f_w, xnh, xnl);
  k_gemm<0><<<dim3(TT / 64, VOC / 128), 256, 0, stream>>>(
      xnh, xnl, embh, embl, (float*)d_out, VOC, DM);
}

// Round 2
// 4917.912 us; speedup vs baseline: 1.2668x; 1.1874x over previous
//
#include <hip/hip_runtime.h>

#define BT 2
#define LSEQ 1024
#define TT 2048      // total tokens
#define DM 768
#define DI 1536
#define DI2 3072
#define DS 16
#define DR 48
#define NL 4
#define VOC 32000
#define EPSV 1e-5f

typedef __attribute__((ext_vector_type(8))) short short8;
typedef __attribute__((ext_vector_type(4))) float f32x4;

__device__ __forceinline__ short f2b(float f) {
  unsigned u = __float_as_uint(f);
  unsigned r = (u + 0x7FFFu + ((u >> 16) & 1u)) >> 16;   // round-to-nearest-even
  return (short)r;
}
__device__ __forceinline__ float b2f(short s) {
  return __uint_as_float(((unsigned)(unsigned short)s) << 16);
}

// split 8 consecutive fp32 into hi/lo bf16 fragments (x ~= hi + lo, err ~2^-17)
__device__ __forceinline__ void split8(const float* __restrict__ p, short8& hi, short8& lo) {
  f32x4 v0 = *(const f32x4*)p;
  f32x4 v1 = *(const f32x4*)(p + 4);
  float f[8] = {v0[0], v0[1], v0[2], v0[3], v1[0], v1[1], v1[2], v1[3]};
#pragma unroll
  for (int j = 0; j < 8; j++) {
    short h = f2b(f[j]);
    hi[j] = h;
    lo[j] = f2b(f[j] - b2f(h));
  }
}

// async 16B global -> LDS (linear dest, wave-uniform base + lane*16)
__device__ __forceinline__ void gload16(const void* g, void* l) {
  __builtin_amdgcn_global_load_lds(
      (const __attribute__((address_space(1))) void*)g,
      (__attribute__((address_space(3))) void*)l, 16, 0, 0);
}

// ---------------- one-time weight split: fp32 -> bf16 hi/lo ----------------
__global__ void k_split(const float* __restrict__ in, short* __restrict__ hi,
                        short* __restrict__ lo) {
  size_t i = ((size_t)blockIdx.x * 256 + threadIdx.x) * 8;
  short8 h, l;
  split8(in + i, h, l);
  *(short8*)(hi + i) = h;
  *(short8*)(lo + i) = l;
}

// ---------------- embedding gather -> fp32 residual stream ----------------
__global__ void k_embed(const int* __restrict__ ids, const float* __restrict__ emb,
                        float* __restrict__ x) {
  int idx = blockIdx.x * 256 + threadIdx.x;
  int t = idx / DM, c = idx % DM;
  x[idx] = emb[(size_t)ids[t] * DM + c];
}

// ---------------- rmsnorm (fp32 -> bf16 hi/lo) ----------------
__global__ void k_rmsnorm(const float* __restrict__ x, const float* __restrict__ w,
                          short* __restrict__ oh, short* __restrict__ ol) {
  int t = blockIdx.x;
  const float* xrow = x + (size_t)t * DM;
  float v[3];
  float p = 0.f;
#pragma unroll
  for (int k = 0; k < 3; k++) {
    v[k] = xrow[threadIdx.x + k * 256];
    p += v[k] * v[k];
  }
  for (int o = 32; o; o >>= 1) p += __shfl_down(p, o, 64);
  __shared__ float sred[4];
  int wave = threadIdx.x >> 6, lane = threadIdx.x & 63;
  if (lane == 0) sred[wave] = p;
  __syncthreads();
  float ss = sred[0] + sred[1] + sred[2] + sred[3];
  float sc = rsqrtf(ss / (float)DM + EPSV);
#pragma unroll
  for (int k = 0; k < 3; k++) {
    int c = threadIdx.x + k * 256;
    float f = v[k] * sc * w[c];
    short h = f2b(f);
    oh[(size_t)t * DM + c] = h;
    ol[(size_t)t * DM + c] = f2b(f - b2f(h));
  }
}

// ------- GEMM: C[M,N] = A[M,K] * W[N,K]^T, pre-split bf16 hi/lo operands -------
// Virtual K' = 3K over segments: (Ah,Bh), (Al,Bh), (Ah,Bl)  [drops lo*lo ~2^-32]
// 128x128 block tile, BK=32, 4 waves (each 64x64 = 4x4 frags), LDS-staged via
// global_load_lds width 16 (m97 structure: 2 barriers per K-step, linear LDS).
// MODE 0: store    MODE 1: += (residual)
template <int MODE>
__global__ void __launch_bounds__(256)
k_gemm128(const short* __restrict__ Ahi, const short* __restrict__ Alo,
          const short* __restrict__ Bhi, const short* __restrict__ Blo,
          float* __restrict__ C, int N, int K) {
  __shared__ __align__(16) short As[128 * 32];
  __shared__ __align__(16) short Bs[128 * 32];
  int t = threadIdx.x;
  int lane = t & 63;
  int quad = lane >> 4, l16 = lane & 15;
  int wave = t >> 6;
  int wr = (wave >> 1) * 64, wc = (wave & 1) * 64;
  int bm = blockIdx.x * 128, bn = blockIdx.y * 128;
  int srow = t >> 2;          // staging row 0..63 (one 4KB instr = 64 rows of 64B)
  int scol = (t & 3) * 8;     // elem offset within 32-elem row
  f32x4 acc[4][4] = {};
  short* la0 = As + t * 8;
  short* la1 = As + 2048 + t * 8;
  short* lb0 = Bs + t * 8;
  short* lb1 = Bs + 2048 + t * 8;
#pragma unroll 1
  for (int seg = 0; seg < 3; seg++) {
    const short* Asrc = (seg == 1) ? Alo : Ahi;
    const short* Bsrc = (seg == 2) ? Blo : Bhi;
    const short* ga0 = Asrc + (size_t)(bm + srow) * K + scol;
    const short* ga1 = Asrc + (size_t)(bm + 64 + srow) * K + scol;
    const short* gb0 = Bsrc + (size_t)(bn + srow) * K + scol;
    const short* gb1 = Bsrc + (size_t)(bn + 64 + srow) * K + scol;
#pragma unroll 1
    for (int k0 = 0; k0 < K; k0 += 32) {
      __syncthreads();                       // readers of prev tile done
      gload16(ga0 + k0, la0);
      gload16(ga1 + k0, la1);
      gload16(gb0 + k0, lb0);
      gload16(gb1 + k0, lb1);
      __syncthreads();                       // vmcnt drained by compiler
      short8 a[4], b[4];
#pragma unroll
      for (int i = 0; i < 4; i++)
        a[i] = *(const short8*)(As + (wr + i * 16 + l16) * 32 + quad * 8);
#pragma unroll
      for (int j = 0; j < 4; j++)
        b[j] = *(const short8*)(Bs + (wc + j * 16 + l16) * 32 + quad * 8);
#pragma unroll
      for (int i = 0; i < 4; i++)
#pragma unroll
        for (int j = 0; j < 4; j++)
          acc[i][j] = __builtin_amdgcn_mfma_f32_16x16x32_bf16(a[i], b[j], acc[i][j], 0, 0, 0);
    }
  }
#pragma unroll
  for (int i = 0; i < 4; i++) {
    int m0 = bm + wr + i * 16 + quad * 4;
#pragma unroll
    for (int j = 0; j < 4; j++) {
      int n = bn + wc + j * 16 + l16;
#pragma unroll
      for (int r = 0; r < 4; r++) {
        size_t off = (size_t)(m0 + r) * N + n;
        if (MODE == 0) C[off] = acc[i][j][r];
        else C[off] += acc[i][j][r];
      }
    }
  }
}

// ------- small-N GEMM variant: 64x64 tile (for out_proj N=768 -> 384 blocks) ----
template <int MODE>
__global__ void __launch_bounds__(256)
k_gemm64(const short* __restrict__ Ahi, const short* __restrict__ Alo,
         const short* __restrict__ Bhi, const short* __restrict__ Blo,
         float* __restrict__ C, int N, int K) {
  __shared__ __align__(16) short As[64 * 32];
  __shared__ __align__(16) short Bs[64 * 32];
  int t = threadIdx.x;
  int lane = t & 63;
  int quad = lane >> 4, l16 = lane & 15;
  int wave = t >> 6;
  int wr = (wave >> 1) * 32, wc = (wave & 1) * 32;
  int bm = blockIdx.x * 64, bn = blockIdx.y * 64;
  int srow = t >> 2;
  int scol = (t & 3) * 8;
  f32x4 acc[2][2] = {};
  short* la = As + t * 8;
  short* lb = Bs + t * 8;
#pragma unroll 1
  for (int seg = 0; seg < 3; seg++) {
    const short* Asrc = (seg == 1) ? Alo : Ahi;
    const short* Bsrc = (seg == 2) ? Blo : Bhi;
    const short* ga = Asrc + (size_t)(bm + srow) * K + scol;
    const short* gb = Bsrc + (size_t)(bn + srow) * K + scol;
#pragma unroll 1
    for (int k0 = 0; k0 < K; k0 += 32) {
      __syncthreads();
      gload16(ga + k0, la);
      gload16(gb + k0, lb);
      __syncthreads();
      short8 a[2], b[2];
#pragma unroll
      for (int i = 0; i < 2; i++)
        a[i] = *(const short8*)(As + (wr + i * 16 + l16) * 32 + quad * 8);
#pragma unroll
      for (int j = 0; j < 2; j++)
        b[j] = *(const short8*)(Bs + (wc + j * 16 + l16) * 32 + quad * 8);
#pragma unroll
      for (int i = 0; i < 2; i++)
#pragma unroll
        for (int j = 0; j < 2; j++)
          acc[i][j] = __builtin_amdgcn_mfma_f32_16x16x32_bf16(a[i], b[j], acc[i][j], 0, 0, 0);
    }
  }
#pragma unroll
  for (int i = 0; i < 2; i++) {
    int m0 = bm + wr + i * 16 + quad * 4;
#pragma unroll
    for (int j = 0; j < 2; j++) {
      int n = bn + wc + j * 16 + l16;
#pragma unroll
      for (int r = 0; r < 4; r++) {
        size_t off = (size_t)(m0 + r) * N + n;
        if (MODE == 0) C[off] = acc[i][j][r];
        else C[off] += acc[i][j][r];
      }
    }
  }
}

// ---------------- causal depthwise conv1d + bias + silu ----------------
__global__ void k_conv_silu(const float* __restrict__ xr, const float* __restrict__ cw,
                            const float* __restrict__ cb, float* __restrict__ u) {
  int idx = blockIdx.x * 256 + threadIdx.x;
  int t = idx / DI, d = idx % DI;
  int l = t & (LSEQ - 1);
  float acc = cb[d];
#pragma unroll
  for (int j = 0; j < 4; j++) {
    int ll = l - 3 + j;
    if (ll >= 0) acc += xr[(size_t)(t - 3 + j) * DI2 + d] * cw[d * 4 + j];
  }
  u[idx] = acc / (1.f + __expf(-acc));
}

// ---------------- x_proj: (1536) -> (80) per token ----------------
__global__ void __launch_bounds__(128)
k_xproj(const float* __restrict__ u, const float* __restrict__ w, float* __restrict__ xdbl) {
  __shared__ float su[DI];
  int t = blockIdx.x;
  for (int k = threadIdx.x; k < DI; k += 128) su[k] = u[(size_t)t * DI + k];
  __syncthreads();
  int o = threadIdx.x;
  if (o < 80) {
    const float* wr = w + (size_t)o * DI;
    float acc = 0.f;
    for (int k = 0; k < DI; k += 4) {
      f32x4 wv = *(const f32x4*)(wr + k);
      acc += su[k] * wv[0] + su[k + 1] * wv[1] + su[k + 2] * wv[2] + su[k + 3] * wv[3];
    }
    xdbl[(size_t)t * 80 + o] = acc;
  }
}

// ---------------- dt_proj (48 -> 1536) + softplus ----------------
__global__ void __launch_bounds__(256)
k_dtproj(const float* __restrict__ xdbl, const float* __restrict__ w,
         const float* __restrict__ bias, float* __restrict__ delta) {
  __shared__ float sd[DR];
  int t = blockIdx.y;
  int d = blockIdx.x * 256 + threadIdx.x;
  if (threadIdx.x < DR) sd[threadIdx.x] = xdbl[(size_t)t * 80 + threadIdx.x];
  __syncthreads();
  const float* wr = w + (size_t)d * DR;
  float acc = bias[d];
#pragma unroll
  for (int k = 0; k < DR; k += 4) {
    f32x4 wv = *(const f32x4*)(wr + k);
    acc += sd[k] * wv[0] + sd[k + 1] * wv[1] + sd[k + 2] * wv[2] + sd[k + 3] * wv[3];
  }
  float sp = (acc > 20.f) ? acc : log1pf(__expf(acc));
  delta[(size_t)t * DI + d] = sp;
}

// ---------------- selective scan: 16 lanes per channel (one per state) ----
// fused epilogue: y = (scan + D*u) * silu(res), bf16 hi/lo out for out_proj
__global__ void __launch_bounds__(256)
k_scan(const float* __restrict__ delta, const float* __restrict__ u,
       const float* __restrict__ xdbl, const float* __restrict__ xr,
       const float* __restrict__ A_log, const float* __restrict__ Dp,
       short* __restrict__ yh, short* __restrict__ yl) {
  int tid = threadIdx.x;
  int n = tid & 15;
  int ch = blockIdx.x * 16 + (tid >> 4);
  int b = ch / DI, d = ch % DI;
  float An = -__expf(A_log[d * DS + n]);
  float Dd = Dp[d];
  const float* dp = delta + (size_t)b * LSEQ * DI + d;
  const float* up = u + (size_t)b * LSEQ * DI + d;
  const float* xd = xdbl + (size_t)b * LSEQ * 80;
  const float* rp = xr + (size_t)b * LSEQ * DI2 + DI + d;
  short* yph = yh + (size_t)b * LSEQ * DI + d;
  short* ypl = yl + (size_t)b * LSEQ * DI + d;
  float h = 0.f;
  for (int l = 0; l < LSEQ; l++) {
    float dt = dp[(size_t)l * DI];
    float uu = up[(size_t)l * DI];
    float Bn = xd[l * 80 + DR + n];
    float Cn = xd[l * 80 + DR + DS + n];
    float dA = __expf(dt * An);
    h = fmaf(dA, h, dt * Bn * uu);
    float p = h * Cn;
    p += __shfl_xor(p, 1, 16);
    p += __shfl_xor(p, 2, 16);
    p += __shfl_xor(p, 4, 16);
    p += __shfl_xor(p, 8, 16);
    if (n == 0) {
      float res = rp[(size_t)l * DI2];
      float yv = fmaf(Dd, uu, p) * (res / (1.f + __expf(-res)));
      short hh = f2b(yv);
      yph[(size_t)l * DI] = hh;
      ypl[(size_t)l * DI] = f2b(yv - b2f(hh));
    }
  }
}

extern "C" void kernel_launch(void* const* d_in, const int* in_sizes, int n_in,
                              void* d_out, int out_size, void* d_ws, size_t ws_size,
                              hipStream_t stream) {
  const int* ids = (const int*)d_in[0];
  const float* emb = (const float*)d_in[4];
  const float* norm_w = (const float*)d_in[5];
  const float* in_proj_w = (const float*)d_in[6];
  const float* conv_w = (const float*)d_in[7];
  const float* conv_b = (const float*)d_in[8];
  const float* x_proj_w = (const float*)d_in[9];
  const float* dt_proj_w = (const float*)d_in[10];
  const float* dt_proj_b = (const float*)d_in[11];
  const float* A_log = (const float*)d_in[12];
  const float* D_param = (const float*)d_in[13];
  const float* out_proj_w = (const float*)d_in[14];
  const float* norm_f_w = (const float*)d_in[15];

  char* wp = (char*)d_ws;
  float* x = (float*)wp;    wp += (size_t)TT * DM * 4;
  float* xr = (float*)wp;   wp += (size_t)TT * DI2 * 4;
  float* u = (float*)wp;    wp += (size_t)TT * DI * 4;
  float* dl = (float*)wp;   wp += (size_t)TT * DI * 4;
  float* xdbl = (float*)wp; wp += (size_t)TT * 80 * 4;
  short* xnh = (short*)wp;  wp += (size_t)TT * DM * 2;
  short* xnl = (short*)wp;  wp += (size_t)TT * DM * 2;
  short* yh = (short*)wp;   wp += (size_t)TT * DI * 2;
  short* yl = (short*)wp;   wp += (size_t)TT * DI * 2;
  short* embh = (short*)wp; wp += (size_t)VOC * DM * 2;
  short* embl = (short*)wp; wp += (size_t)VOC * DM * 2;
  short* iph = (short*)wp;  wp += (size_t)NL * DI2 * DM * 2;
  short* ipl = (short*)wp;  wp += (size_t)NL * DI2 * DM * 2;
  short* oph = (short*)wp;  wp += (size_t)NL * DM * DI * 2;
  short* opl = (short*)wp;  wp += (size_t)NL * DM * DI * 2;

  // one-time (per launch) weight splits: fp32 -> bf16 hi/lo
  k_split<<<(VOC * DM) / 2048, 256, 0, stream>>>(emb, embh, embl);
  k_split<<<(NL * DI2 * DM) / 2048, 256, 0, stream>>>(in_proj_w, iph, ipl);
  k_split<<<(NL * DM * DI) / 2048, 256, 0, stream>>>(out_proj_w, oph, opl);

  k_embed<<<TT * DM / 256, 256, 0, stream>>>(ids, emb, x);
  for (int i = 0; i < NL; i++) {
    k_rmsnorm<<<TT, 256, 0, stream>>>(x, norm_w + (size_t)i * DM, xnh, xnl);
    k_gemm128<0><<<dim3(TT / 128, DI2 / 128), 256, 0, stream>>>(
        xnh, xnl, iph + (size_t)i * DI2 * DM, ipl + (size_t)i * DI2 * DM, xr, DI2, DM);
    k_conv_silu<<<TT * DI / 256, 256, 0, stream>>>(
        xr, conv_w + (size_t)i * DI * 4, conv_b + (size_t)i * DI, u);
    k_xproj<<<TT, 128, 0, stream>>>(u, x_proj_w + (size_t)i * 80 * DI, xdbl);
    k_dtproj<<<dim3(DI / 256, TT), 256, 0, stream>>>(
        xdbl, dt_proj_w + (size_t)i * DI * DR, dt_proj_b + (size_t)i * DI, dl);
    k_scan<<<BT * DI / 16, 256, 0, stream>>>(
        dl, u, xdbl, xr, A_log + (size_t)i * DI * DS, D_param + (size_t)i * DI, yh, yl);
    k_gemm64<1><<<dim3(TT / 64, DM / 64), 256, 0, stream>>>(
        yh, yl, oph + (size_t)i * DM * DI, opl + (size_t)i * DM * DI, x, DM, DI);
  }
  k_rmsnorm<<<TT, 256, 0, stream>>>(x, norm_f_w, xnh, xnl);
  k_gemm128<0><<<dim3(TT / 128, VOC / 128), 256, 0, stream>>>(
      xnh, xnl, embh, embl, (float*)d_out, VOC, DM);
}

// Round 4
// 2291.398 us; speedup vs baseline: 2.7188x; 2.1462x over previous
//
#include <hip/hip_runtime.h>

#define BT 2
#define LSEQ 1024
#define TT 2048      // total tokens
#define DM 768
#define DI 1536
#define DI2 3072
#define DS 16
#define DR 48
#define NL 4
#define VOC 32000
#define EPSV 1e-5f
#define NC 16        // scan chunks
#define CL 64        // chunk length (NC*CL = LSEQ)
#define CHTOT (BT*DI*DS)   // per-chunk state count = 49152

typedef __attribute__((ext_vector_type(8))) short short8;
typedef __attribute__((ext_vector_type(4))) short short4v;
typedef __attribute__((ext_vector_type(4))) float f32x4;

__device__ __forceinline__ short f2b(float f) {
  unsigned u = __float_as_uint(f);
  unsigned r = (u + 0x7FFFu + ((u >> 16) & 1u)) >> 16;   // round-to-nearest-even
  return (short)r;
}
__device__ __forceinline__ float b2f(short s) {
  return __uint_as_float(((unsigned)(unsigned short)s) << 16);
}

// split 8 consecutive fp32 into hi/lo bf16 fragments (x ~= hi + lo, err ~2^-17)
__device__ __forceinline__ void split8(const float* __restrict__ p, short8& hi, short8& lo) {
  f32x4 v0 = *(const f32x4*)p;
  f32x4 v1 = *(const f32x4*)(p + 4);
  float f[8] = {v0[0], v0[1], v0[2], v0[3], v1[0], v1[1], v1[2], v1[3]};
#pragma unroll
  for (int j = 0; j < 8; j++) {
    short h = f2b(f[j]);
    hi[j] = h;
    lo[j] = f2b(f[j] - b2f(h));
  }
}

// async 16B global -> LDS (linear dest, wave-uniform base + lane*16)
__device__ __forceinline__ void gload16(const void* g, void* l) {
  __builtin_amdgcn_global_load_lds(
      (const __attribute__((address_space(1))) void*)g,
      (__attribute__((address_space(3))) void*)l, 16, 0, 0);
}

// ---------------- one-time weight split: fp32 -> bf16 hi/lo ----------------
__global__ void k_split(const float* __restrict__ in, short* __restrict__ hi,
                        short* __restrict__ lo) {
  size_t i = ((size_t)blockIdx.x * 256 + threadIdx.x) * 8;
  short8 h, l;
  split8(in + i, h, l);
  *(short8*)(hi + i) = h;
  *(short8*)(lo + i) = l;
}

// ---------------- embedding gather -> fp32 residual stream ----------------
__global__ void k_embed(const int* __restrict__ ids, const float* __restrict__ emb,
                        float* __restrict__ x) {
  int idx = blockIdx.x * 256 + threadIdx.x;
  int t = idx / DM, c = idx % DM;
  x[idx] = emb[(size_t)ids[t] * DM + c];
}

// ---------------- rmsnorm (fp32 -> bf16 hi/lo) ----------------
__global__ void k_rmsnorm(const float* __restrict__ x, const float* __restrict__ w,
                          short* __restrict__ oh, short* __restrict__ ol) {
  int t = blockIdx.x;
  const float* xrow = x + (size_t)t * DM;
  float v[3];
  float p = 0.f;
#pragma unroll
  for (int k = 0; k < 3; k++) {
    v[k] = xrow[threadIdx.x + k * 256];
    p += v[k] * v[k];
  }
  for (int o = 32; o; o >>= 1) p += __shfl_down(p, o, 64);
  __shared__ float sred[4];
  int wave = threadIdx.x >> 6, lane = threadIdx.x & 63;
  if (lane == 0) sred[wave] = p;
  __syncthreads();
  float ss = sred[0] + sred[1] + sred[2] + sred[3];
  float sc = rsqrtf(ss / (float)DM + EPSV);
#pragma unroll
  for (int k = 0; k < 3; k++) {
    int c = threadIdx.x + k * 256;
    float f = v[k] * sc * w[c];
    short h = f2b(f);
    oh[(size_t)t * DM + c] = h;
    ol[(size_t)t * DM + c] = f2b(f - b2f(h));
  }
}

// ------- GEMM: C[M,N] = A[M,K] * W[N,K]^T, pre-split bf16 hi/lo operands -------
// Virtual K' = 3K over segments: (Ah,Bh), (Al,Bh), (Ah,Bl)  [drops lo*lo ~2^-32]
// 128x128 block tile, BK=32, 4 waves (each 64x64 = 4x4 frags), LDS-staged via
// global_load_lds width 16 (m97 structure: 2 barriers per K-step, linear LDS).
// MODE 0: store    MODE 1: += (residual)
template <int MODE>
__global__ void __launch_bounds__(256)
k_gemm128(const short* __restrict__ Ahi, const short* __restrict__ Alo,
          const short* __restrict__ Bhi, const short* __restrict__ Blo,
          float* __restrict__ C, int N, int K) {
  __shared__ __align__(16) short As[128 * 32];
  __shared__ __align__(16) short Bs[128 * 32];
  int t = threadIdx.x;
  int lane = t & 63;
  int quad = lane >> 4, l16 = lane & 15;
  int wave = t >> 6;
  int wr = (wave >> 1) * 64, wc = (wave & 1) * 64;
  int bm = blockIdx.x * 128, bn = blockIdx.y * 128;
  int srow = t >> 2;          // staging row 0..63 (one 4KB instr = 64 rows of 64B)
  int scol = (t & 3) * 8;     // elem offset within 32-elem row
  f32x4 acc[4][4] = {};
  short* la0 = As + t * 8;
  short* la1 = As + 2048 + t * 8;
  short* lb0 = Bs + t * 8;
  short* lb1 = Bs + 2048 + t * 8;
#pragma unroll 1
  for (int seg = 0; seg < 3; seg++) {
    const short* Asrc = (seg == 1) ? Alo : Ahi;
    const short* Bsrc = (seg == 2) ? Blo : Bhi;
    const short* ga0 = Asrc + (size_t)(bm + srow) * K + scol;
    const short* ga1 = Asrc + (size_t)(bm + 64 + srow) * K + scol;
    const short* gb0 = Bsrc + (size_t)(bn + srow) * K + scol;
    const short* gb1 = Bsrc + (size_t)(bn + 64 + srow) * K + scol;
#pragma unroll 1
    for (int k0 = 0; k0 < K; k0 += 32) {
      __syncthreads();                       // readers of prev tile done
      gload16(ga0 + k0, la0);
      gload16(ga1 + k0, la1);
      gload16(gb0 + k0, lb0);
      gload16(gb1 + k0, lb1);
      __syncthreads();                       // vmcnt drained by compiler
      short8 a[4], b[4];
#pragma unroll
      for (int i = 0; i < 4; i++)
        a[i] = *(const short8*)(As + (wr + i * 16 + l16) * 32 + quad * 8);
#pragma unroll
      for (int j = 0; j < 4; j++)
        b[j] = *(const short8*)(Bs + (wc + j * 16 + l16) * 32 + quad * 8);
#pragma unroll
      for (int i = 0; i < 4; i++)
#pragma unroll
        for (int j = 0; j < 4; j++)
          acc[i][j] = __builtin_amdgcn_mfma_f32_16x16x32_bf16(a[i], b[j], acc[i][j], 0, 0, 0);
    }
  }
#pragma unroll
  for (int i = 0; i < 4; i++) {
    int m0 = bm + wr + i * 16 + quad * 4;
#pragma unroll
    for (int j = 0; j < 4; j++) {
      int n = bn + wc + j * 16 + l16;
#pragma unroll
      for (int r = 0; r < 4; r++) {
        size_t off = (size_t)(m0 + r) * N + n;
        if (MODE == 0) C[off] = acc[i][j][r];
        else C[off] += acc[i][j][r];
      }
    }
  }
}

// ------- small-N GEMM variant: 64x64 tile (for out_proj N=768 -> 384 blocks) ----
template <int MODE>
__global__ void __launch_bounds__(256)
k_gemm64(const short* __restrict__ Ahi, const short* __restrict__ Alo,
         const short* __restrict__ Bhi, const short* __restrict__ Blo,
         float* __restrict__ C, int N, int K) {
  __shared__ __align__(16) short As[64 * 32];
  __shared__ __align__(16) short Bs[64 * 32];
  int t = threadIdx.x;
  int lane = t & 63;
  int quad = lane >> 4, l16 = lane & 15;
  int wave = t >> 6;
  int wr = (wave >> 1) * 32, wc = (wave & 1) * 32;
  int bm = blockIdx.x * 64, bn = blockIdx.y * 64;
  int srow = t >> 2;
  int scol = (t & 3) * 8;
  f32x4 acc[2][2] = {};
  short* la = As + t * 8;
  short* lb = Bs + t * 8;
#pragma unroll 1
  for (int seg = 0; seg < 3; seg++) {
    const short* Asrc = (seg == 1) ? Alo : Ahi;
    const short* Bsrc = (seg == 2) ? Blo : Bhi;
    const short* ga = Asrc + (size_t)(bm + srow) * K + scol;
    const short* gb = Bsrc + (size_t)(bn + srow) * K + scol;
#pragma unroll 1
    for (int k0 = 0; k0 < K; k0 += 32) {
      __syncthreads();
      gload16(ga + k0, la);
      gload16(gb + k0, lb);
      __syncthreads();
      short8 a[2], b[2];
#pragma unroll
      for (int i = 0; i < 2; i++)
        a[i] = *(const short8*)(As + (wr + i * 16 + l16) * 32 + quad * 8);
#pragma unroll
      for (int j = 0; j < 2; j++)
        b[j] = *(const short8*)(Bs + (wc + j * 16 + l16) * 32 + quad * 8);
#pragma unroll
      for (int i = 0; i < 2; i++)
#pragma unroll
        for (int j = 0; j < 2; j++)
          acc[i][j] = __builtin_amdgcn_mfma_f32_16x16x32_bf16(a[i], b[j], acc[i][j], 0, 0, 0);
    }
  }
#pragma unroll
  for (int i = 0; i < 2; i++) {
    int m0 = bm + wr + i * 16 + quad * 4;
#pragma unroll
    for (int j = 0; j < 2; j++) {
      int n = bn + wc + j * 16 + l16;
#pragma unroll
      for (int r = 0; r < 4; r++) {
        size_t off = (size_t)(m0 + r) * N + n;
        if (MODE == 0) C[off] = acc[i][j][r];
        else C[off] += acc[i][j][r];
      }
    }
  }
}

// ---------------- causal depthwise conv1d + bias + silu ----------------
__global__ void k_conv_silu(const float* __restrict__ xr, const float* __restrict__ cw,
                            const float* __restrict__ cb, float* __restrict__ u) {
  int idx = blockIdx.x * 256 + threadIdx.x;
  int t = idx / DI, d = idx % DI;
  int l = t & (LSEQ - 1);
  float acc = cb[d];
#pragma unroll
  for (int j = 0; j < 4; j++) {
    int ll = l - 3 + j;
    if (ll >= 0) acc += xr[(size_t)(t - 3 + j) * DI2 + d] * cw[d * 4 + j];
  }
  u[idx] = acc / (1.f + __expf(-acc));
}

// ---------------- x_proj: (1536) -> (80) per token ----------------
__global__ void __launch_bounds__(128)
k_xproj(const float* __restrict__ u, const float* __restrict__ w, float* __restrict__ xdbl) {
  __shared__ float su[DI];
  int t = blockIdx.x;
  for (int k = threadIdx.x; k < DI; k += 128) su[k] = u[(size_t)t * DI + k];
  __syncthreads();
  int o = threadIdx.x;
  if (o < 80) {
    const float* wr = w + (size_t)o * DI;
    float acc = 0.f;
    for (int k = 0; k < DI; k += 4) {
      f32x4 wv = *(const f32x4*)(wr + k);
      acc += su[k] * wv[0] + su[k + 1] * wv[1] + su[k + 2] * wv[2] + su[k + 3] * wv[3];
    }
    xdbl[(size_t)t * 80 + o] = acc;
  }
}

// ---------------- dt_proj (48 -> 1536) + softplus ----------------
__global__ void __launch_bounds__(256)
k_dtproj(const float* __restrict__ xdbl, const float* __restrict__ w,
         const float* __restrict__ bias, float* __restrict__ delta) {
  __shared__ float sd[DR];
  int t = blockIdx.y;
  int d = blockIdx.x * 256 + threadIdx.x;
  if (threadIdx.x < DR) sd[threadIdx.x] = xdbl[(size_t)t * 80 + threadIdx.x];
  __syncthreads();
  const float* wr = w + (size_t)d * DR;
  float acc = bias[d];
#pragma unroll
  for (int k = 0; k < DR; k += 4) {
    f32x4 wv = *(const f32x4*)(wr + k);
    acc += sd[k] * wv[0] + sd[k + 1] * wv[1] + sd[k + 2] * wv[2] + sd[k + 3] * wv[3];
  }
  float sp = (acc > 20.f) ? acc : log1pf(__expf(acc));
  delta[(size_t)t * DI + d] = sp;
}

// ======== chunked selective scan (3 phases) ========
// block = 16 channels x 16 states; blockIdx.x = channel-group (0..191),
// blockIdx.y = chunk c. All inputs staged as coalesced [CL][16] LDS tiles.
// Scan buffers P,S alias the (dead-in-this-window) xnh/xnl workspace; Hin is
// written in-place over P by k_scanmid -> zero extra workspace vs round 2.

// phase 1: per-chunk local scan with h0=0 -> P = prod(dA), S = local end-state
__global__ void __launch_bounds__(256)
k_scan1(const float* __restrict__ delta, const float* __restrict__ u,
        const float* __restrict__ xdbl, const float* __restrict__ A_log,
        float* __restrict__ P, float* __restrict__ S) {
  __shared__ float sdt[CL][16];
  __shared__ float su[CL][16];
  __shared__ float sB[CL][16];
  int tid = threadIdx.x;
  int g = blockIdx.x, c = blockIdx.y;
  int b = g / (DI / 16);
  int d0 = (g % (DI / 16)) * 16;
  int lb = c * CL;
  {
    int row = tid >> 2, col = (tid & 3) * 4;
    size_t rbase = (size_t)(b * LSEQ + lb + row);
    *(f32x4*)&sdt[row][col] = *(const f32x4*)(delta + rbase * DI + d0 + col);
    *(f32x4*)&su[row][col]  = *(const f32x4*)(u + rbase * DI + d0 + col);
    *(f32x4*)&sB[row][col]  = *(const f32x4*)(xdbl + rbase * 80 + DR + col);
  }
  __syncthreads();
  int cg = tid >> 4, n = tid & 15;
  int d = d0 + cg;
  float An = -__expf(A_log[d * DS + n]);
  float h = 0.f, Pp = 1.f;
#pragma unroll 4
  for (int l = 0; l < CL; l++) {
    float dt = sdt[l][cg];
    float uu = su[l][cg];
    float Bn = sB[l][n];
    float dA = __expf(dt * An);
    Pp *= dA;
    h = fmaf(dA, h, dt * Bn * uu);
  }
  size_t off = (size_t)c * CHTOT + (size_t)(b * DI + d) * DS + n;
  P[off] = Pp;
  S[off] = h;
}

// phase mid: scan the 16 chunk boundaries; Hin[c] (state entering chunk c)
// is written IN PLACE over P[c].
__global__ void __launch_bounds__(256)
k_scanmid(float* __restrict__ PH, const float* __restrict__ S) {
  int idx = blockIdx.x * 256 + threadIdx.x;   // (b*DI+d)*DS+n
  float H = 0.f;
#pragma unroll
  for (int c = 0; c < NC; c++) {
    size_t off = (size_t)c * CHTOT + idx;
    float Pp = PH[off];
    float Ss = S[off];
    PH[off] = H;
    H = fmaf(Pp, H, Ss);
  }
}

// phase 2: re-run chunk from Hin, fused epilogue y=(scan+D*u)*silu(res) -> bf16 hi/lo
__global__ void __launch_bounds__(256)
k_scan2(const float* __restrict__ delta, const float* __restrict__ u,
        const float* __restrict__ xdbl, const float* __restrict__ xr,
        const float* __restrict__ A_log, const float* __restrict__ Dp,
        const float* __restrict__ Hin,
        short* __restrict__ yh, short* __restrict__ yl) {
  __shared__ float sdt[CL][16];
  __shared__ float su[CL][16];
  __shared__ float sB[CL][16];
  __shared__ float sC[CL][16];
  __shared__ float sres[CL][16];
  __shared__ float sy[CL][16];
  int tid = threadIdx.x;
  int g = blockIdx.x, c = blockIdx.y;
  int b = g / (DI / 16);
  int d0 = (g % (DI / 16)) * 16;
  int lb = c * CL;
  {
    int row = tid >> 2, col = (tid & 3) * 4;
    size_t rbase = (size_t)(b * LSEQ + lb + row);
    *(f32x4*)&sdt[row][col]  = *(const f32x4*)(delta + rbase * DI + d0 + col);
    *(f32x4*)&su[row][col]   = *(const f32x4*)(u + rbase * DI + d0 + col);
    *(f32x4*)&sB[row][col]   = *(const f32x4*)(xdbl + rbase * 80 + DR + col);
    *(f32x4*)&sC[row][col]   = *(const f32x4*)(xdbl + rbase * 80 + DR + DS + col);
    *(f32x4*)&sres[row][col] = *(const f32x4*)(xr + rbase * DI2 + DI + d0 + col);
  }
  __syncthreads();
  int cg = tid >> 4, n = tid & 15;
  int d = d0 + cg;
  float An = -__expf(A_log[d * DS + n]);
  float Dd = Dp[d];
  float h = Hin[(size_t)c * CHTOT + (size_t)(b * DI + d) * DS + n];
  for (int l = 0; l < CL; l++) {
    float dt = sdt[l][cg];
    float uu = su[l][cg];
    float Bn = sB[l][n];
    float Cn = sC[l][n];
    float dA = __expf(dt * An);
    h = fmaf(dA, h, dt * Bn * uu);
    float p = h * Cn;
    p += __shfl_xor(p, 1, 16);
    p += __shfl_xor(p, 2, 16);
    p += __shfl_xor(p, 4, 16);
    p += __shfl_xor(p, 8, 16);
    if (n == 0) {
      float res = sres[l][cg];
      sy[l][cg] = fmaf(Dd, uu, p) * (res / (1.f + __expf(-res)));
    }
  }
  __syncthreads();
  {
    int row = tid >> 2, col = (tid & 3) * 4;
    size_t obase = (size_t)(b * LSEQ + lb + row) * DI + d0 + col;
    short4v hv, lv;
#pragma unroll
    for (int j = 0; j < 4; j++) {
      float f = sy[row][col + j];
      short hh = f2b(f);
      hv[j] = hh;
      lv[j] = f2b(f - b2f(hh));
    }
    *(short4v*)(yh + obase) = hv;
    *(short4v*)(yl + obase) = lv;
  }
}

extern "C" void kernel_launch(void* const* d_in, const int* in_sizes, int n_in,
                              void* d_out, int out_size, void* d_ws, size_t ws_size,
                              hipStream_t stream) {
  const int* ids = (const int*)d_in[0];
  const float* emb = (const float*)d_in[4];
  const float* norm_w = (const float*)d_in[5];
  const float* in_proj_w = (const float*)d_in[6];
  const float* conv_w = (const float*)d_in[7];
  const float* conv_b = (const float*)d_in[8];
  const float* x_proj_w = (const float*)d_in[9];
  const float* dt_proj_w = (const float*)d_in[10];
  const float* dt_proj_b = (const float*)d_in[11];
  const float* A_log = (const float*)d_in[12];
  const float* D_param = (const float*)d_in[13];
  const float* out_proj_w = (const float*)d_in[14];
  const float* norm_f_w = (const float*)d_in[15];

  char* wp = (char*)d_ws;
  float* x = (float*)wp;    wp += (size_t)TT * DM * 4;
  float* xr = (float*)wp;   wp += (size_t)TT * DI2 * 4;
  float* u = (float*)wp;    wp += (size_t)TT * DI * 4;
  float* dl = (float*)wp;   wp += (size_t)TT * DI * 4;
  float* xdbl = (float*)wp; wp += (size_t)TT * 80 * 4;
  short* xnh = (short*)wp;  wp += (size_t)TT * DM * 2;
  short* xnl = (short*)wp;  wp += (size_t)TT * DM * 2;
  short* yh = (short*)wp;   wp += (size_t)TT * DI * 2;
  short* yl = (short*)wp;   wp += (size_t)TT * DI * 2;
  short* embh = (short*)wp; wp += (size_t)VOC * DM * 2;
  short* embl = (short*)wp; wp += (size_t)VOC * DM * 2;
  short* iph = (short*)wp;  wp += (size_t)NL * DI2 * DM * 2;
  short* ipl = (short*)wp;  wp += (size_t)NL * DI2 * DM * 2;
  short* oph = (short*)wp;  wp += (size_t)NL * DM * DI * 2;
  short* opl = (short*)wp;  wp += (size_t)NL * DM * DI * 2;

  // scan buffers alias xnh/xnl (dead between in_proj GEMM and next rmsnorm):
  // NC*CHTOT*4 = 3,145,728 B each == TT*DM*2 exactly.
  float* Pb = (float*)xnh;
  float* Sb = (float*)xnl;

  // one-time (per launch) weight splits: fp32 -> bf16 hi/lo
  k_split<<<(VOC * DM) / 2048, 256, 0, stream>>>(emb, embh, embl);
  k_split<<<(NL * DI2 * DM) / 2048, 256, 0, stream>>>(in_proj_w, iph, ipl);
  k_split<<<(NL * DM * DI) / 2048, 256, 0, stream>>>(out_proj_w, oph, opl);

  k_embed<<<TT * DM / 256, 256, 0, stream>>>(ids, emb, x);
  for (int i = 0; i < NL; i++) {
    k_rmsnorm<<<TT, 256, 0, stream>>>(x, norm_w + (size_t)i * DM, xnh, xnl);
    k_gemm128<0><<<dim3(TT / 128, DI2 / 128), 256, 0, stream>>>(
        xnh, xnl, iph + (size_t)i * DI2 * DM, ipl + (size_t)i * DI2 * DM, xr, DI2, DM);
    k_conv_silu<<<TT * DI / 256, 256, 0, stream>>>(
        xr, conv_w + (size_t)i * DI * 4, conv_b + (size_t)i * DI, u);
    k_xproj<<<TT, 128, 0, stream>>>(u, x_proj_w + (size_t)i * 80 * DI, xdbl);
    k_dtproj<<<dim3(DI / 256, TT), 256, 0, stream>>>(
        xdbl, dt_proj_w + (size_t)i * DI * DR, dt_proj_b + (size_t)i * DI, dl);
    k_scan1<<<dim3(BT * DI / 16, NC), 256, 0, stream>>>(
        dl, u, xdbl, A_log + (size_t)i * DI * DS, Pb, Sb);
    k_scanmid<<<CHTOT / 256, 256, 0, stream>>>(Pb, Sb);
    k_scan2<<<dim3(BT * DI / 16, NC), 256, 0, stream>>>(
        dl, u, xdbl, xr, A_log + (size_t)i * DI * DS, D_param + (size_t)i * DI, Pb, yh, yl);
    k_gemm64<1><<<dim3(TT / 64, DM / 64), 256, 0, stream>>>(
        yh, yl, oph + (size_t)i * DM * DI, opl + (size_t)i * DM * DI, x, DM, DI);
  }
  k_rmsnorm<<<TT, 256, 0, stream>>>(x, norm_f_w, xnh, xnl);
  k_gemm128<0><<<dim3(TT / 128, VOC / 128), 256, 0, stream>>>(
      xnh, xnl, embh, embl, (float*)d_out, VOC, DM);
}

// Round 5
// 2001.275 us; speedup vs baseline: 3.1130x; 1.1450x over previous
//
#include <hip/hip_runtime.h>

#define BT 2
#define LSEQ 1024
#define TT 2048      // total tokens
#define DM 768
#define DI 1536
#define DI2 3072
#define DS 16
#define DR 48
#define NL 4
#define VOC 32000
#define EPSV 1e-5f
#define NC 16        // scan chunks
#define CL 64        // chunk length (NC*CL = LSEQ)
#define CHTOT (BT*DI*DS)   // per-chunk state count = 49152

typedef __attribute__((ext_vector_type(8))) short short8;
typedef __attribute__((ext_vector_type(4))) short short4v;
typedef __attribute__((ext_vector_type(4))) float f32x4;
typedef __attribute__((ext_vector_type(8))) _Float16 half8;

__device__ __forceinline__ short f2b(float f) {
  unsigned u = __float_as_uint(f);
  unsigned r = (u + 0x7FFFu + ((u >> 16) & 1u)) >> 16;   // round-to-nearest-even
  return (short)r;
}
__device__ __forceinline__ float b2f(short s) {
  return __uint_as_float(((unsigned)(unsigned short)s) << 16);
}

// split 8 consecutive fp32 into hi/lo bf16 fragments (x ~= hi + lo, err ~2^-17)
__device__ __forceinline__ void split8(const float* __restrict__ p, short8& hi, short8& lo) {
  f32x4 v0 = *(const f32x4*)p;
  f32x4 v1 = *(const f32x4*)(p + 4);
  float f[8] = {v0[0], v0[1], v0[2], v0[3], v1[0], v1[1], v1[2], v1[3]};
#pragma unroll
  for (int j = 0; j < 8; j++) {
    short h = f2b(f[j]);
    hi[j] = h;
    lo[j] = f2b(f[j] - b2f(h));
  }
}

// fp16 variant (x ~= hi + lo, err ~2^-23): used for the terminal LM-head GEMM
__device__ __forceinline__ void split8h(const float* __restrict__ p, short8& hi, short8& lo) {
  f32x4 v0 = *(const f32x4*)p;
  f32x4 v1 = *(const f32x4*)(p + 4);
  float f[8] = {v0[0], v0[1], v0[2], v0[3], v1[0], v1[1], v1[2], v1[3]};
#pragma unroll
  for (int j = 0; j < 8; j++) {
    _Float16 h = (_Float16)f[j];
    hi[j] = __builtin_bit_cast(short, h);
    lo[j] = __builtin_bit_cast(short, (_Float16)(f[j] - (float)h));
  }
}

// async 16B global -> LDS (linear dest, wave-uniform base + lane*16)
__device__ __forceinline__ void gload16(const void* g, void* l) {
  __builtin_amdgcn_global_load_lds(
      (const __attribute__((address_space(1))) void*)g,
      (__attribute__((address_space(3))) void*)l, 16, 0, 0);
}

// ---------------- one-time weight split: fp32 -> bf16 (F16=0) / fp16 (F16=1) hi/lo ----
template <int F16>
__global__ void k_split(const float* __restrict__ in, short* __restrict__ hi,
                        short* __restrict__ lo) {
  size_t i = ((size_t)blockIdx.x * 256 + threadIdx.x) * 8;
  short8 h, l;
  if constexpr (F16) split8h(in + i, h, l);
  else               split8(in + i, h, l);
  *(short8*)(hi + i) = h;
  *(short8*)(lo + i) = l;
}

// ---------------- embedding gather -> fp32 residual stream ----------------
__global__ void k_embed(const int* __restrict__ ids, const float* __restrict__ emb,
                        float* __restrict__ x) {
  int idx = blockIdx.x * 256 + threadIdx.x;
  int t = idx / DM, c = idx % DM;
  x[idx] = emb[(size_t)ids[t] * DM + c];
}

// ---------------- rmsnorm (fp32 -> bf16/fp16 hi/lo) ----------------
template <int F16>
__global__ void k_rmsnorm(const float* __restrict__ x, const float* __restrict__ w,
                          short* __restrict__ oh, short* __restrict__ ol) {
  int t = blockIdx.x;
  const float* xrow = x + (size_t)t * DM;
  float v[3];
  float p = 0.f;
#pragma unroll
  for (int k = 0; k < 3; k++) {
    v[k] = xrow[threadIdx.x + k * 256];
    p += v[k] * v[k];
  }
  for (int o = 32; o; o >>= 1) p += __shfl_down(p, o, 64);
  __shared__ float sred[4];
  int wave = threadIdx.x >> 6, lane = threadIdx.x & 63;
  if (lane == 0) sred[wave] = p;
  __syncthreads();
  float ss = sred[0] + sred[1] + sred[2] + sred[3];
  float sc = rsqrtf(ss / (float)DM + EPSV);
#pragma unroll
  for (int k = 0; k < 3; k++) {
    int c = threadIdx.x + k * 256;
    float f = v[k] * sc * w[c];
    if constexpr (F16) {
      _Float16 h = (_Float16)f;
      oh[(size_t)t * DM + c] = __builtin_bit_cast(short, h);
      ol[(size_t)t * DM + c] = __builtin_bit_cast(short, (_Float16)(f - (float)h));
    } else {
      short h = f2b(f);
      oh[(size_t)t * DM + c] = h;
      ol[(size_t)t * DM + c] = f2b(f - b2f(h));
    }
  }
}

// ------- GEMM: C[M,N] = A[M,K] * W[N,K]^T, pre-split hi/lo operands -------
// SEGS=3 (bf16): (Ah,Bh),(Al,Bh),(Ah,Bl)  [drops lo*lo ~2^-32]
// SEGS=2 (fp16): (Ah,Bh),(Ah,Bl)          [drops Al*B ~2^-12 — terminal GEMM only]
// 128x128 block tile, BK=32, 4 waves (each 64x64 = 4x4 frags), LDS-staged via
// global_load_lds width 16 (m97 structure: 2 barriers per K-step, linear LDS).
// MODE 0: store    MODE 1: += (residual)
template <int MODE, int SEGS, int F16>
__global__ void __launch_bounds__(256)
k_gemm128(const short* __restrict__ Ahi, const short* __restrict__ Alo,
          const short* __restrict__ Bhi, const short* __restrict__ Blo,
          float* __restrict__ C, int N, int K) {
  __shared__ __align__(16) short As[128 * 32];
  __shared__ __align__(16) short Bs[128 * 32];
  int t = threadIdx.x;
  int lane = t & 63;
  int quad = lane >> 4, l16 = lane & 15;
  int wave = t >> 6;
  int wr = (wave >> 1) * 64, wc = (wave & 1) * 64;
  int bm = blockIdx.x * 128, bn = blockIdx.y * 128;
  int srow = t >> 2;          // staging row 0..63 (one 4KB instr = 64 rows of 64B)
  int scol = (t & 3) * 8;     // elem offset within 32-elem row
  f32x4 acc[4][4] = {};
  short* la0 = As + t * 8;
  short* la1 = As + 2048 + t * 8;
  short* lb0 = Bs + t * 8;
  short* lb1 = Bs + 2048 + t * 8;
#pragma unroll 1
  for (int seg = 0; seg < SEGS; seg++) {
    const short* Asrc = (SEGS == 3 && seg == 1) ? Alo : Ahi;
    const short* Bsrc = (seg == SEGS - 1 && seg > 0) ? Blo : Bhi;
    const short* ga0 = Asrc + (size_t)(bm + srow) * K + scol;
    const short* ga1 = Asrc + (size_t)(bm + 64 + srow) * K + scol;
    const short* gb0 = Bsrc + (size_t)(bn + srow) * K + scol;
    const short* gb1 = Bsrc + (size_t)(bn + 64 + srow) * K + scol;
#pragma unroll 1
    for (int k0 = 0; k0 < K; k0 += 32) {
      __syncthreads();                       // readers of prev tile done
      gload16(ga0 + k0, la0);
      gload16(ga1 + k0, la1);
      gload16(gb0 + k0, lb0);
      gload16(gb1 + k0, lb1);
      __syncthreads();                       // vmcnt drained by compiler
      short8 a[4], b[4];
#pragma unroll
      for (int i = 0; i < 4; i++)
        a[i] = *(const short8*)(As + (wr + i * 16 + l16) * 32 + quad * 8);
#pragma unroll
      for (int j = 0; j < 4; j++)
        b[j] = *(const short8*)(Bs + (wc + j * 16 + l16) * 32 + quad * 8);
#pragma unroll
      for (int i = 0; i < 4; i++)
#pragma unroll
        for (int j = 0; j < 4; j++) {
          if constexpr (F16)
            acc[i][j] = __builtin_amdgcn_mfma_f32_16x16x32_f16(
                __builtin_bit_cast(half8, a[i]), __builtin_bit_cast(half8, b[j]),
                acc[i][j], 0, 0, 0);
          else
            acc[i][j] = __builtin_amdgcn_mfma_f32_16x16x32_bf16(a[i], b[j], acc[i][j], 0, 0, 0);
        }
    }
  }
#pragma unroll
  for (int i = 0; i < 4; i++) {
    int m0 = bm + wr + i * 16 + quad * 4;
#pragma unroll
    for (int j = 0; j < 4; j++) {
      int n = bn + wc + j * 16 + l16;
#pragma unroll
      for (int r = 0; r < 4; r++) {
        size_t off = (size_t)(m0 + r) * N + n;
        if (MODE == 0) C[off] = acc[i][j][r];
        else C[off] += acc[i][j][r];
      }
    }
  }
}

// ------- small-N GEMM variant: 64x64 tile (for out_proj N=768 -> 384 blocks) ----
template <int MODE>
__global__ void __launch_bounds__(256)
k_gemm64(const short* __restrict__ Ahi, const short* __restrict__ Alo,
         const short* __restrict__ Bhi, const short* __restrict__ Blo,
         float* __restrict__ C, int N, int K) {
  __shared__ __align__(16) short As[64 * 32];
  __shared__ __align__(16) short Bs[64 * 32];
  int t = threadIdx.x;
  int lane = t & 63;
  int quad = lane >> 4, l16 = lane & 15;
  int wave = t >> 6;
  int wr = (wave >> 1) * 32, wc = (wave & 1) * 32;
  int bm = blockIdx.x * 64, bn = blockIdx.y * 64;
  int srow = t >> 2;
  int scol = (t & 3) * 8;
  f32x4 acc[2][2] = {};
  short* la = As + t * 8;
  short* lb = Bs + t * 8;
#pragma unroll 1
  for (int seg = 0; seg < 3; seg++) {
    const short* Asrc = (seg == 1) ? Alo : Ahi;
    const short* Bsrc = (seg == 2) ? Blo : Bhi;
    const short* ga = Asrc + (size_t)(bm + srow) * K + scol;
    const short* gb = Bsrc + (size_t)(bn + srow) * K + scol;
#pragma unroll 1
    for (int k0 = 0; k0 < K; k0 += 32) {
      __syncthreads();
      gload16(ga + k0, la);
      gload16(gb + k0, lb);
      __syncthreads();
      short8 a[2], b[2];
#pragma unroll
      for (int i = 0; i < 2; i++)
        a[i] = *(const short8*)(As + (wr + i * 16 + l16) * 32 + quad * 8);
#pragma unroll
      for (int j = 0; j < 2; j++)
        b[j] = *(const short8*)(Bs + (wc + j * 16 + l16) * 32 + quad * 8);
#pragma unroll
      for (int i = 0; i < 2; i++)
#pragma unroll
        for (int j = 0; j < 2; j++)
          acc[i][j] = __builtin_amdgcn_mfma_f32_16x16x32_bf16(a[i], b[j], acc[i][j], 0, 0, 0);
    }
  }
#pragma unroll
  for (int i = 0; i < 2; i++) {
    int m0 = bm + wr + i * 16 + quad * 4;
#pragma unroll
    for (int j = 0; j < 2; j++) {
      int n = bn + wc + j * 16 + l16;
#pragma unroll
      for (int r = 0; r < 4; r++) {
        size_t off = (size_t)(m0 + r) * N + n;
        if (MODE == 0) C[off] = acc[i][j][r];
        else C[off] += acc[i][j][r];
      }
    }
  }
}

// ---------------- causal depthwise conv1d + bias + silu ----------------
__global__ void k_conv_silu(const float* __restrict__ xr, const float* __restrict__ cw,
                            const float* __restrict__ cb, float* __restrict__ u) {
  int idx = blockIdx.x * 256 + threadIdx.x;
  int t = idx / DI, d = idx % DI;
  int l = t & (LSEQ - 1);
  float acc = cb[d];
#pragma unroll
  for (int j = 0; j < 4; j++) {
    int ll = l - 3 + j;
    if (ll >= 0) acc += xr[(size_t)(t - 3 + j) * DI2 + d] * cw[d * 4 + j];
  }
  u[idx] = acc / (1.f + __expf(-acc));
}

// ---------------- x_proj: (1536) -> (80), 8 tokens per block ----------------
// pairs mapped (tok = p&7, out = p>>3) so 8 adjacent lanes share one W row
// (broadcast read) -> W L2 traffic /8 vs 1-token-per-block; all 256 lanes active.
// su padded to 1540 floats/row: lane stride 1540 % 32 = 4 -> conflict-free.
__global__ void __launch_bounds__(256)
k_xproj(const float* __restrict__ u, const float* __restrict__ w, float* __restrict__ xdbl) {
  __shared__ float su[8][1540];
  int t0 = blockIdx.x * 8;
  for (int i = threadIdx.x; i < 8 * (DI / 4); i += 256) {
    int tok = i / (DI / 4), k4 = i % (DI / 4);
    *(f32x4*)&su[tok][k4 * 4] = *(const f32x4*)(u + (size_t)(t0 + tok) * DI + k4 * 4);
  }
  __syncthreads();
  for (int p = threadIdx.x; p < 8 * 80; p += 256) {
    int tok = p & 7, o = p >> 3;
    const float* wr = w + (size_t)o * DI;
    float acc = 0.f;
    for (int k = 0; k < DI; k += 4) {
      f32x4 wv = *(const f32x4*)(wr + k);
      f32x4 uv = *(const f32x4*)&su[tok][k];
      acc += uv[0] * wv[0] + uv[1] * wv[1] + uv[2] * wv[2] + uv[3] * wv[3];
    }
    xdbl[(size_t)(t0 + tok) * 80 + o] = acc;
  }
}

// ---------------- dt_proj (48 -> 1536) + softplus ----------------
__global__ void __launch_bounds__(256)
k_dtproj(const float* __restrict__ xdbl, const float* __restrict__ w,
         const float* __restrict__ bias, float* __restrict__ delta) {
  __shared__ float sd[DR];
  int t = blockIdx.y;
  int d = blockIdx.x * 256 + threadIdx.x;
  if (threadIdx.x < DR) sd[threadIdx.x] = xdbl[(size_t)t * 80 + threadIdx.x];
  __syncthreads();
  const float* wr = w + (size_t)d * DR;
  float acc = bias[d];
#pragma unroll
  for (int k = 0; k < DR; k += 4) {
    f32x4 wv = *(const f32x4*)(wr + k);
    acc += sd[k] * wv[0] + sd[k + 1] * wv[1] + sd[k + 2] * wv[2] + sd[k + 3] * wv[3];
  }
  float sp = (acc > 20.f) ? acc : log1pf(__expf(acc));
  delta[(size_t)t * DI + d] = sp;
}

// ======== chunked selective scan (3 phases) ========
// block = 16 channels x 16 states; blockIdx.x = channel-group (0..191),
// blockIdx.y = chunk c. All inputs staged as coalesced [CL][16] LDS tiles.
// Scan buffers P,S alias the (dead-in-this-window) xnh/xnl workspace; Hin is
// written in-place over P by k_scanmid -> zero extra workspace vs round 2.

// phase 1: per-chunk local scan with h0=0 -> P = prod(dA), S = local end-state
__global__ void __launch_bounds__(256)
k_scan1(const float* __restrict__ delta, const float* __restrict__ u,
        const float* __restrict__ xdbl, const float* __restrict__ A_log,
        float* __restrict__ P, float* __restrict__ S) {
  __shared__ float sdt[CL][16];
  __shared__ float su[CL][16];
  __shared__ float sB[CL][16];
  int tid = threadIdx.x;
  int g = blockIdx.x, c = blockIdx.y;
  int b = g / (DI / 16);
  int d0 = (g % (DI / 16)) * 16;
  int lb = c * CL;
  {
    int row = tid >> 2, col = (tid & 3) * 4;
    size_t rbase = (size_t)(b * LSEQ + lb + row);
    *(f32x4*)&sdt[row][col] = *(const f32x4*)(delta + rbase * DI + d0 + col);
    *(f32x4*)&su[row][col]  = *(const f32x4*)(u + rbase * DI + d0 + col);
    *(f32x4*)&sB[row][col]  = *(const f32x4*)(xdbl + rbase * 80 + DR + col);
  }
  __syncthreads();
  int cg = tid >> 4, n = tid & 15;
  int d = d0 + cg;
  float An = -__expf(A_log[d * DS + n]);
  float h = 0.f, Pp = 1.f;
#pragma unroll 4
  for (int l = 0; l < CL; l++) {
    float dt = sdt[l][cg];
    float uu = su[l][cg];
    float Bn = sB[l][n];
    float dA = __expf(dt * An);
    Pp *= dA;
    h = fmaf(dA, h, dt * Bn * uu);
  }
  size_t off = (size_t)c * CHTOT + (size_t)(b * DI + d) * DS + n;
  P[off] = Pp;
  S[off] = h;
}

// phase mid: scan the 16 chunk boundaries; Hin[c] (state entering chunk c)
// is written IN PLACE over P[c].
__global__ void __launch_bounds__(256)
k_scanmid(float* __restrict__ PH, const float* __restrict__ S) {
  int idx = blockIdx.x * 256 + threadIdx.x;   // (b*DI+d)*DS+n
  float H = 0.f;
#pragma unroll
  for (int c = 0; c < NC; c++) {
    size_t off = (size_t)c * CHTOT + idx;
    float Pp = PH[off];
    float Ss = S[off];
    PH[off] = H;
    H = fmaf(Pp, H, Ss);
  }
}

// phase 2: re-run chunk from Hin, fused epilogue y=(scan+D*u)*silu(res) -> bf16 hi/lo
__global__ void __launch_bounds__(256)
k_scan2(const float* __restrict__ delta, const float* __restrict__ u,
        const float* __restrict__ xdbl, const float* __restrict__ xr,
        const float* __restrict__ A_log, const float* __restrict__ Dp,
        const float* __restrict__ Hin,
        short* __restrict__ yh, short* __restrict__ yl) {
  __shared__ float sdt[CL][16];
  __shared__ float su[CL][16];
  __shared__ float sB[CL][16];
  __shared__ float sC[CL][16];
  __shared__ float sres[CL][16];
  __shared__ float sy[CL][16];
  int tid = threadIdx.x;
  int g = blockIdx.x, c = blockIdx.y;
  int b = g / (DI / 16);
  int d0 = (g % (DI / 16)) * 16;
  int lb = c * CL;
  {
    int row = tid >> 2, col = (tid & 3) * 4;
    size_t rbase = (size_t)(b * LSEQ + lb + row);
    *(f32x4*)&sdt[row][col]  = *(const f32x4*)(delta + rbase * DI + d0 + col);
    *(f32x4*)&su[row][col]   = *(const f32x4*)(u + rbase * DI + d0 + col);
    *(f32x4*)&sB[row][col]   = *(const f32x4*)(xdbl + rbase * 80 + DR + col);
    *(f32x4*)&sC[row][col]   = *(const f32x4*)(xdbl + rbase * 80 + DR + DS + col);
    *(f32x4*)&sres[row][col] = *(const f32x4*)(xr + rbase * DI2 + DI + d0 + col);
  }
  __syncthreads();
  int cg = tid >> 4, n = tid & 15;
  int d = d0 + cg;
  float An = -__expf(A_log[d * DS + n]);
  float Dd = Dp[d];
  float h = Hin[(size_t)c * CHTOT + (size_t)(b * DI + d) * DS + n];
  for (int l = 0; l < CL; l++) {
    float dt = sdt[l][cg];
    float uu = su[l][cg];
    float Bn = sB[l][n];
    float Cn = sC[l][n];
    float dA = __expf(dt * An);
    h = fmaf(dA, h, dt * Bn * uu);
    float p = h * Cn;
    p += __shfl_xor(p, 1, 16);
    p += __shfl_xor(p, 2, 16);
    p += __shfl_xor(p, 4, 16);
    p += __shfl_xor(p, 8, 16);
    if (n == 0) {
      float res = sres[l][cg];
      sy[l][cg] = fmaf(Dd, uu, p) * (res / (1.f + __expf(-res)));
    }
  }
  __syncthreads();
  {
    int row = tid >> 2, col = (tid & 3) * 4;
    size_t obase = (size_t)(b * LSEQ + lb + row) * DI + d0 + col;
    short4v hv, lv;
#pragma unroll
    for (int j = 0; j < 4; j++) {
      float f = sy[row][col + j];
      short hh = f2b(f);
      hv[j] = hh;
      lv[j] = f2b(f - b2f(hh));
    }
    *(short4v*)(yh + obase) = hv;
    *(short4v*)(yl + obase) = lv;
  }
}

extern "C" void kernel_launch(void* const* d_in, const int* in_sizes, int n_in,
                              void* d_out, int out_size, void* d_ws, size_t ws_size,
                              hipStream_t stream) {
  const int* ids = (const int*)d_in[0];
  const float* emb = (const float*)d_in[4];
  const float* norm_w = (const float*)d_in[5];
  const float* in_proj_w = (const float*)d_in[6];
  const float* conv_w = (const float*)d_in[7];
  const float* conv_b = (const float*)d_in[8];
  const float* x_proj_w = (const float*)d_in[9];
  const float* dt_proj_w = (const float*)d_in[10];
  const float* dt_proj_b = (const float*)d_in[11];
  const float* A_log = (const float*)d_in[12];
  const float* D_param = (const float*)d_in[13];
  const float* out_proj_w = (const float*)d_in[14];
  const float* norm_f_w = (const float*)d_in[15];

  char* wp = (char*)d_ws;
  float* x = (float*)wp;    wp += (size_t)TT * DM * 4;
  float* xr = (float*)wp;   wp += (size_t)TT * DI2 * 4;
  float* u = (float*)wp;    wp += (size_t)TT * DI * 4;
  float* dl = (float*)wp;   wp += (size_t)TT * DI * 4;
  float* xdbl = (float*)wp; wp += (size_t)TT * 80 * 4;
  short* xnh = (short*)wp;  wp += (size_t)TT * DM * 2;
  short* xnl = (short*)wp;  wp += (size_t)TT * DM * 2;
  short* yh = (short*)wp;   wp += (size_t)TT * DI * 2;
  short* yl = (short*)wp;   wp += (size_t)TT * DI * 2;
  short* embh = (short*)wp; wp += (size_t)VOC * DM * 2;
  short* embl = (short*)wp; wp += (size_t)VOC * DM * 2;
  short* iph = (short*)wp;  wp += (size_t)NL * DI2 * DM * 2;
  short* ipl = (short*)wp;  wp += (size_t)NL * DI2 * DM * 2;
  short* oph = (short*)wp;  wp += (size_t)NL * DM * DI * 2;
  short* opl = (short*)wp;  wp += (size_t)NL * DM * DI * 2;

  // scan buffers alias xnh/xnl (dead between in_proj GEMM and next rmsnorm):
  // NC*CHTOT*4 = 3,145,728 B each == TT*DM*2 exactly.
  float* Pb = (float*)xnh;
  float* Sb = (float*)xnl;

  // one-time (per launch) weight splits: emb -> fp16 hi/lo (terminal LM head),
  // layer weights -> bf16 hi/lo
  k_split<1><<<(VOC * DM) / 2048, 256, 0, stream>>>(emb, embh, embl);
  k_split<0><<<(NL * DI2 * DM) / 2048, 256, 0, stream>>>(in_proj_w, iph, ipl);
  k_split<0><<<(NL * DM * DI) / 2048, 256, 0, stream>>>(out_proj_w, oph, opl);

  k_embed<<<TT * DM / 256, 256, 0, stream>>>(ids, emb, x);
  for (int i = 0; i < NL; i++) {
    k_rmsnorm<0><<<TT, 256, 0, stream>>>(x, norm_w + (size_t)i * DM, xnh, xnl);
    k_gemm128<0, 3, 0><<<dim3(TT / 128, DI2 / 128), 256, 0, stream>>>(
        xnh, xnl, iph + (size_t)i * DI2 * DM, ipl + (size_t)i * DI2 * DM, xr, DI2, DM);
    k_conv_silu<<<TT * DI / 256, 256, 0, stream>>>(
        xr, conv_w + (size_t)i * DI * 4, conv_b + (size_t)i * DI, u);
    k_xproj<<<TT / 8, 256, 0, stream>>>(u, x_proj_w + (size_t)i * 80 * DI, xdbl);
    k_dtproj<<<dim3(DI / 256, TT), 256, 0, stream>>>(
        xdbl, dt_proj_w + (size_t)i * DI * DR, dt_proj_b + (size_t)i * DI, dl);
    k_scan1<<<dim3(BT * DI / 16, NC), 256, 0, stream>>>(
        dl, u, xdbl, A_log + (size_t)i * DI * DS, Pb, Sb);
    k_scanmid<<<CHTOT / 256, 256, 0, stream>>>(Pb, Sb);
    k_scan2<<<dim3(BT * DI / 16, NC), 256, 0, stream>>>(
        dl, u, xdbl, xr, A_log + (size_t)i * DI * DS, D_param + (size_t)i * DI, Pb, yh, yl);
    k_gemm64<1><<<dim3(TT / 64, DM / 64), 256, 0, stream>>>(
        yh, yl, oph + (size_t)i * DM * DI, opl + (size_t)i * DM * DI, x, DM, DI);
  }
  k_rmsnorm<1><<<TT, 256, 0, stream>>>(x, norm_f_w, xnh, xnl);
  k_gemm128<0, 2, 1><<<dim3(TT / 128, VOC / 128), 256, 0, stream>>>(
      xnh, xnl, embh, embl, (float*)d_out, VOC, DM);
}